// Round 7
// baseline (472.512 us; speedup 1.0000x reference)
//
#include <hip/hip_runtime.h>

#define LSEQ 384
#define DIM 128
#define NHEADS 4
#define HDIM 16

typedef __attribute__((ext_vector_type(8))) short bf16x8;
typedef __attribute__((ext_vector_type(4))) short bf16x4;
typedef __attribute__((ext_vector_type(4))) float f32x4;

#define MFMA32(A,B,C) __builtin_amdgcn_mfma_f32_16x16x32_bf16(A,B,C,0,0,0)

#if __has_builtin(__builtin_amdgcn_mfma_f32_16x16x16bf16_1k)
#define HAVE_MFMA16 1
#else
#define HAVE_MFMA16 0
#endif

// ---------- helpers ----------
__device__ __forceinline__ float bf2f_lo(unsigned int u) { return __uint_as_float(u << 16); }
__device__ __forceinline__ float bf2f_hi(unsigned int u) { return __uint_as_float(u & 0xFFFF0000u); }
__device__ __forceinline__ float bf2f_s(unsigned short s) { return __uint_as_float(((unsigned int)s) << 16); }
__device__ __forceinline__ unsigned short f2bf(float f) {
    unsigned int u = __float_as_uint(f);
    u += 0x7FFFu + ((u >> 16) & 1u);   // round-to-nearest-even
    return (unsigned short)(u >> 16);
}
// pack two f32 -> one dword of 2x bf16 (RTNE), single instruction (T12 recipe)
__device__ __forceinline__ unsigned int pkbf(float a, float b) {
    unsigned int r;
    asm("v_cvt_pk_bf16_f32 %0, %1, %2" : "=v"(r) : "v"(a), "v"(b));
    return r;
}
__device__ __forceinline__ float ex2(float x) {
#if __has_builtin(__builtin_amdgcn_exp2f)
    return __builtin_amdgcn_exp2f(x);
#else
    return exp2f(x);
#endif
}
__device__ __forceinline__ float frcp(float x) {
#if __has_builtin(__builtin_amdgcn_rcpf)
    return __builtin_amdgcn_rcpf(x);
#else
    return 1.f / x;
#endif
}
__device__ __forceinline__ float fsigm(float x) {      // sigmoid(x) = 1/(1+2^(-x*log2e))
    return frcp(1.f + ex2(-1.44269504088896341f * x));
}
__device__ __forceinline__ float fsilu(float x) { return x * fsigm(x); }
__device__ __forceinline__ bf16x8 ldw8(const unsigned short* p) {
    union { uint4 x; bf16x8 v; } c;
    c.x = *(const uint4*)p;
    return c.v;
}

// ---- converted-weight layout (shorts), placed in workspace slack:
//  [0]        wqg_r [256][128]  (qkv rows 0..191 (q rows 0..63 pre-scaled), gate rows 192..255)
//  [32768]    wqg_c [256][128]
//  [65536]    w1b   [256][128]
//  [98304]    w2b   [128][256]
//  [131072]   wfin_r[128][64]
//  [139264]   wfin_c[128][64]   (total 147456 shorts = 294912 B)

// ================= wconv: one-shot f32 -> bf16 weight conversion ==========
__global__ __launch_bounds__(256) void wconv_kernel(
    const float* __restrict__ r_qkv_w, const float* __restrict__ r_gate_w,
    const float* __restrict__ c_qkv_w, const float* __restrict__ c_gate_w,
    const float* __restrict__ ff_w1, const float* __restrict__ ff_w2,
    const float* __restrict__ r_fin_w, const float* __restrict__ c_fin_w,
    unsigned short* __restrict__ wout)
{
    int idx = blockIdx.x * 256 + threadIdx.x;   // dword index, 73728 total
    const float SQ = 0.36067376022224085f;      // 0.25 * log2(e) / sqrt(HDIM) scaling for q
    float2 a;
    if (idx < 32768) {                 // wqg_r / wqg_c
        int half = idx >> 14;
        int e = (idx & 16383) * 2;
        int row = e >> 7, col = e & 127;
        const float* qkv = half ? c_qkv_w : r_qkv_w;
        const float* gw  = half ? c_gate_w : r_gate_w;
        const float* src = (row < 192) ? (qkv + (long)row * 128 + col)
                                       : (gw + (long)(row - 192) * 128 + col);
        a = *(const float2*)src;
        if (row < 64) { a.x *= SQ; a.y *= SQ; }
    } else if (idx < 49152) {          // w1b
        a = *(const float2*)(ff_w1 + (long)(idx - 32768) * 2);
    } else if (idx < 65536) {          // w2b
        a = *(const float2*)(ff_w2 + (long)(idx - 49152) * 2);
    } else if (idx < 69632) {          // wfin_r
        a = *(const float2*)(r_fin_w + (long)(idx - 65536) * 2);
    } else {                           // wfin_c
        a = *(const float2*)(c_fin_w + (long)(idx - 69632) * 2);
    }
    ((unsigned int*)wout)[idx] = pkbf(a.x, a.y);
}

// ================= qkvg: LN + qkv/gate projection via MFMA =================
// Writes q*(0.25*log2e), k, v, sigmoid(gate) as bf16 into [b][h][n][16] layout.
// Swapped operands: D[c][token] -> coalesced uint2 (4x bf16) stores.
// LN: 4 tokens in flight per wave (16-lane groups), float4 loads, 4-step shfl.
#define XSTR 138   // LDS row stride in bf16
__global__ __launch_bounds__(256, 3) void qkvg_kernel(
    const float* __restrict__ x, long sb, long sn,
    const float* __restrict__ ln_g, const float* __restrict__ ln_b,
    const unsigned short* __restrict__ wqg,      // [256][128] bf16, q-scale baked in
    const float* __restrict__ b_gate,
    unsigned short* __restrict__ qws, unsigned short* __restrict__ kws,
    unsigned short* __restrict__ vws, unsigned short* __restrict__ gws)
{
    const int b   = blockIdx.x;
    const int q4  = blockIdx.y;          // token quarter (96 tokens each)
    const int tid = threadIdx.x, wave = tid >> 6, lane = tid & 63;
    const int jl  = lane & 15, g = lane >> 4;

    __shared__ __align__(16) unsigned short xn[96 * XSTR];
    __shared__ __align__(16) unsigned short xr[96 * XSTR];

    // ---- weight B-frags (16x16x32): wave owns n-tiles wave*4 .. wave*4+3
    bf16x8 wfrag[4][4];
#pragma unroll
    for (int t = 0; t < 4; ++t) {
        int c = (wave * 4 + t) * 16 + jl;
        const unsigned short* wr = wqg + (long)c * 128;
#pragma unroll
        for (int ks = 0; ks < 4; ++ks) wfrag[t][ks] = ldw8(wr + ks * 32 + g * 8);
    }
    // gate bias: per (t, g, r) (swapped output): only wave 3 needs it
    float4 gb4[4];
    if (wave == 3) {
#pragma unroll
        for (int t = 0; t < 4; ++t) gb4[t] = *(const float4*)(b_gate + t * 16 + g * 4);
    }

    // ---- LayerNorm: quarter-wave (16 lanes) per token, 4 tokens/iter, 6 iters
    const float* xbase = x + (long)b * sb + (long)(q4 * 96) * sn;
    const float4 lgA = *(const float4*)(ln_g + jl * 8);
    const float4 lgB = *(const float4*)(ln_g + jl * 8 + 4);
    const float4 lbA = *(const float4*)(ln_b + jl * 8);
    const float4 lbB = *(const float4*)(ln_b + jl * 8 + 4);
#pragma unroll
    for (int i = 0; i < 6; ++i) {
        int tk = wave * 24 + i * 4 + g;
        const float* xp = xbase + (long)tk * sn + jl * 8;
        float4 a0 = *(const float4*)xp;
        float4 a1 = *(const float4*)(xp + 4);
        float s  = ((a0.x + a0.y) + (a0.z + a0.w)) + ((a1.x + a1.y) + (a1.z + a1.w));
        float sq = a0.x * a0.x;
        sq = fmaf(a0.y, a0.y, sq); sq = fmaf(a0.z, a0.z, sq); sq = fmaf(a0.w, a0.w, sq);
        sq = fmaf(a1.x, a1.x, sq); sq = fmaf(a1.y, a1.y, sq);
        sq = fmaf(a1.z, a1.z, sq); sq = fmaf(a1.w, a1.w, sq);
        s  += __shfl_xor(s, 1, 64);  sq += __shfl_xor(sq, 1, 64);
        s  += __shfl_xor(s, 2, 64);  sq += __shfl_xor(sq, 2, 64);
        s  += __shfl_xor(s, 4, 64);  sq += __shfl_xor(sq, 4, 64);
        s  += __shfl_xor(s, 8, 64);  sq += __shfl_xor(sq, 8, 64);
        float mean = s * (1.f / 128.f);
        float var  = sq * (1.f / 128.f) - mean * mean;
        float inv  = rsqrtf(var + 1e-5f);
        float n0 = (a0.x - mean) * inv * lgA.x + lbA.x;
        float n1 = (a0.y - mean) * inv * lgA.y + lbA.y;
        float n2 = (a0.z - mean) * inv * lgA.z + lbA.z;
        float n3 = (a0.w - mean) * inv * lgA.w + lbA.w;
        float n4 = (a1.x - mean) * inv * lgB.x + lbB.x;
        float n5 = (a1.y - mean) * inv * lgB.y + lbB.y;
        float n6 = (a1.z - mean) * inv * lgB.z + lbB.z;
        float n7 = (a1.w - mean) * inv * lgB.w + lbB.w;
        unsigned int* dn = (unsigned int*)(xn + tk * XSTR) + jl * 4;
        dn[0] = pkbf(n0, n1); dn[1] = pkbf(n2, n3);
        dn[2] = pkbf(n4, n5); dn[3] = pkbf(n6, n7);
        unsigned int* dr = (unsigned int*)(xr + tk * XSTR) + jl * 4;
        dr[0] = pkbf(a0.x, a0.y); dr[1] = pkbf(a0.z, a0.w);
        dr[2] = pkbf(a1.x, a1.y); dr[3] = pkbf(a1.z, a1.w);
    }
    __syncthreads();

    // ---- GEMM: 6 m-tiles x 4 n-tiles x 4 k-steps (16x16x32), swapped operands
    const unsigned int* a32 = (const unsigned int*)((wave == 3) ? xr : xn);
    for (int mt = 0; mt < 6; ++mt) {
        bf16x8 af[4];
#pragma unroll
        for (int ks = 0; ks < 4; ++ks) {
            int adw = (mt * 16 + jl) * (XSTR / 2) + ks * 16 + g * 4;
            union { unsigned int u[4]; bf16x8 v; } cv;
            cv.u[0] = a32[adw]; cv.u[1] = a32[adw + 1];
            cv.u[2] = a32[adw + 2]; cv.u[3] = a32[adw + 3];
            af[ks] = cv.v;
        }
#pragma unroll
        for (int t = 0; t < 4; ++t) {
            int nt = wave * 4 + t;
            f32x4 acc = {0.f, 0.f, 0.f, 0.f};
#pragma unroll
            for (int ks = 0; ks < 4; ++ks) acc = MFMA32(wfrag[t][ks], af[ks], acc);
            // D[c][token]: row (g*4+r) = feature dim, col (jl) = token
            int mat = nt >> 2, hh = nt & 3;
            int token = q4 * 96 + mt * 16 + jl;
            long base = (((long)b * NHEADS + hh) * LSEQ + token) * HDIM + g * 4;
            if (mat == 3) {
                float4 gb = gb4[t];
                float v0 = fsigm(acc[0] + gb.x), v1 = fsigm(acc[1] + gb.y);
                float v2 = fsigm(acc[2] + gb.z), v3 = fsigm(acc[3] + gb.w);
                uint2 pk = { pkbf(v0, v1), pkbf(v2, v3) };
                *(uint2*)(gws + base) = pk;
            } else {
                unsigned short* outp = (mat == 0) ? qws : (mat == 1) ? kws : vws;
                uint2 pk = { pkbf(acc[0], acc[1]), pkbf(acc[2], acc[3]) };
                *(uint2*)(outp + base) = pk;
            }
        }
    }
}

// ================= attention core: S=QK^T, softmax over j, O=P^T V, gate ===
// No LDS staging; u-outer loops with rotate-prefetch. grid = 1536 = 6 blocks/CU,
// declared via launch_bounds for +50% occupancy (VGPR 68 <= 85 cap).
#if HAVE_MFMA16
typedef bf16x4 sfrag_t;
#define SMFMA(A,B,C) __builtin_amdgcn_mfma_f32_16x16x16bf16_1k(A,B,C,0,0,0)
__device__ __forceinline__ sfrag_t ldfragG(const unsigned short* base, int row, int g) {
    union { uint2 x; bf16x4 v; } c;
    c.x = *(const uint2*)(base + row * 16 + g * 4);
    return c.v;
}
#else
typedef bf16x8 sfrag_t;
#define SMFMA(A,B,C) MFMA32(A,B,C)
__device__ __forceinline__ sfrag_t ldfragG(const unsigned short* base, int row, int g) {
    union { uint4 x; bf16x8 v; } c;
    if (g < 2) c.x = *(const uint4*)(base + row * 16 + g * 8);
    else { c.x.x = 0; c.x.y = 0; c.x.z = 0; c.x.w = 0; }
    return c.v;
}
#endif

__global__ __launch_bounds__(256, 6) void attn_core_kernel(
    const unsigned short* __restrict__ qws, const unsigned short* __restrict__ kws,
    const unsigned short* __restrict__ vws, const unsigned short* __restrict__ gws,
    unsigned short* __restrict__ attn_out)    // bf16 [b][j][64]
{
    const int b = blockIdx.x, h = blockIdx.y;
    const int tid = threadIdx.x, wave = tid >> 6, lane = tid & 63;
    const int jl  = lane & 15, g = lane >> 4;

    __shared__ float linv[LSEQ];     // 1536 B total LDS

    const long goff = ((long)b * NHEADS + h) * (LSEQ * HDIM);
    const unsigned short* Q = qws + goff;
    const unsigned short* K = kws + goff;
    const unsigned short* V = vws + goff;

    // gate prefetch for this wave's 6 j-tiles (hide full latency under pass 1)
    uint2 gq6[6];
#pragma unroll
    for (int t = 0; t < 6; ++t)
        gq6[t] = *(const uint2*)(gws + goff + (long)((wave * 6 + t) * 16 + jl) * 16 + g * 4);

    // own-tile frags (tile = wave*6 + t)
    sfrag_t Qo[6], Ko[6];
#pragma unroll
    for (int t = 0; t < 6; ++t) {
        Qo[t] = ldfragG(Q, (wave * 6 + t) * 16 + jl, g);
        Ko[t] = ldfragG(K, (wave * 6 + t) * 16 + jl, g);
    }

    const f32x4 fz = {0.f, 0.f, 0.f, 0.f};

    // ---- pass 1: l_i = sum_j 2^(s'_ij); u outer (K-frags loaded once per u)
    float lsum[6] = {0.f, 0.f, 0.f, 0.f, 0.f, 0.f};
    {
        sfrag_t kc0 = ldfragG(K, jl, g), kc1 = ldfragG(K, 16 + jl, g);
        for (int u = 0; u < 12; ++u) {
            sfrag_t c0 = kc0, c1 = kc1;
            if (u < 11) {
                kc0 = ldfragG(K, 32 * (u + 1) + jl, g);
                kc1 = ldfragG(K, 32 * (u + 1) + 16 + jl, g);
            }
#pragma unroll
            for (int t = 0; t < 6; ++t) {
                f32x4 s0 = SMFMA(c0, Qo[t], fz);
                f32x4 s1 = SMFMA(c1, Qo[t], fz);
                lsum[t] += ((ex2(s0[0]) + ex2(s0[1])) + (ex2(s0[2]) + ex2(s0[3])))
                         + ((ex2(s1[0]) + ex2(s1[1])) + (ex2(s1[2]) + ex2(s1[3])));
            }
        }
    }
#pragma unroll
    for (int t = 0; t < 6; ++t) {
        float l = lsum[t];
        l += __shfl_xor(l, 16, 64);
        l += __shfl_xor(l, 32, 64);
        if (lane < 16) linv[(wave * 6 + t) * 16 + jl] = 1.f / l;
    }

    // prefetch u=0 of pass 2 (independent of linv)
    sfrag_t qc0 = ldfragG(Q, jl, g), qc1 = ldfragG(Q, 16 + jl, g);
    unsigned short vv[8];
#pragma unroll
    for (int p = 0; p < 4; ++p) {
        int t0 = (p < 2) ? (g * 4 + 2 * p) : (16 + g * 4 + 2 * (p - 2));
        vv[2 * p]     = V[t0 * 16 + jl];
        vv[2 * p + 1] = V[(t0 + 1) * 16 + jl];
    }
    __syncthreads();

    // ---- pass 2 (u outer): O[d][j] accumulated per j-tile; VB built per u
    f32x4 o[6];
#pragma unroll
    for (int t = 0; t < 6; ++t) o[t] = fz;

    for (int u = 0; u < 12; ++u) {
        // V-hat B-frag for this u (tau slot permutation), from prefetched raw v
        union { unsigned int w[4]; bf16x8 v; } vbu;
#pragma unroll
        for (int p = 0; p < 4; ++p) {
            int t0 = 32 * u + ((p < 2) ? (g * 4 + 2 * p) : (16 + g * 4 + 2 * (p - 2)));
            vbu.w[p] = pkbf(bf2f_s(vv[2 * p]) * linv[t0],
                            bf2f_s(vv[2 * p + 1]) * linv[t0 + 1]);
        }
        bf16x8 VB = vbu.v;
        sfrag_t c0 = qc0, c1 = qc1;
        if (u < 11) {
            qc0 = ldfragG(Q, 32 * (u + 1) + jl, g);
            qc1 = ldfragG(Q, 32 * (u + 1) + 16 + jl, g);
#pragma unroll
            for (int p = 0; p < 4; ++p) {
                int t0 = 32 * (u + 1) + ((p < 2) ? (g * 4 + 2 * p) : (16 + g * 4 + 2 * (p - 2)));
                vv[2 * p]     = V[t0 * 16 + jl];
                vv[2 * p + 1] = V[(t0 + 1) * 16 + jl];
            }
        }
#pragma unroll
        for (int t = 0; t < 6; ++t) {
            f32x4 s0 = SMFMA(c0, Ko[t], fz);
            f32x4 s1 = SMFMA(c1, Ko[t], fz);
            union { unsigned int w[4]; bf16x8 v; } pf;
            pf.w[0] = pkbf(ex2(s0[0]), ex2(s0[1]));
            pf.w[1] = pkbf(ex2(s0[2]), ex2(s0[3]));
            pf.w[2] = pkbf(ex2(s1[0]), ex2(s1[1]));
            pf.w[3] = pkbf(ex2(s1[2]), ex2(s1[3]));
            o[t] = MFMA32(VB, pf.v, o[t]);    // D[d][j]
        }
    }

    // ---- epilogue: gate & store bf16 uint2
#pragma unroll
    for (int t = 0; t < 6; ++t) {
        int jrow = (wave * 6 + t) * 16 + jl;
        uint2 gpk = gq6[t];
        float r0 = o[t][0] * bf2f_lo(gpk.x);
        float r1 = o[t][1] * bf2f_hi(gpk.x);
        float r2 = o[t][2] * bf2f_lo(gpk.y);
        float r3 = o[t][3] * bf2f_hi(gpk.y);
        uint2 pk = { pkbf(r0, r1), pkbf(r2, r3) };
        *(uint2*)(attn_out + ((long)b * LSEQ + jrow) * 64 + h * HDIM + g * 4) = pk;
    }
}

// ========== fin projection: out[t,c] = R[t,c] + bias[c] + sum_k A[t,k]*W[c,k] ==========
// A bf16 [tok][64], W bf16 [128][64]. No LDS/barriers. grid 1536 = 6 blocks/CU.
__global__ __launch_bounds__(256, 6) void fin_kernel(
    const unsigned short* __restrict__ A,
    const unsigned short* __restrict__ Wb, const float* __restrict__ Bv,
    const float* __restrict__ R, long rs0, long rs1,
    float* __restrict__ out, long os0, long os1)
{
    const int tid = threadIdx.x, wave = tid >> 6, lane = tid & 63;
    const int jl = lane & 15, g = lane >> 4;

    bf16x8 wfrag[2][2];
    float4 bias4[2];
#pragma unroll
    for (int t = 0; t < 2; ++t) {
        int c = (wave * 2 + t) * 16 + jl;
        const unsigned short* wr = Wb + (long)c * 64;
        bias4[t] = *(const float4*)(Bv + (wave * 2 + t) * 16 + g * 4);
        wfrag[t][0] = ldw8(wr + g * 8);
        wfrag[t][1] = ldw8(wr + 32 + g * 8);
    }

    const long t0 = (long)blockIdx.x * 96;
    const int i0 = blockIdx.x >> 2;
    const int j0b = (blockIdx.x & 3) * 96;

    for (int mt = 0; mt < 6; ++mt) {
        const unsigned short* ap = A + (t0 + mt * 16 + jl) * 64;
        bf16x8 af0 = ldw8(ap + g * 8);
        bf16x8 af1 = ldw8(ap + 32 + g * 8);
#pragma unroll
        for (int t = 0; t < 2; ++t) {
            f32x4 acc = {0.f, 0.f, 0.f, 0.f};
            acc = MFMA32(wfrag[t][0], af0, acc);
            acc = MFMA32(wfrag[t][1], af1, acc);
            int tj = j0b + mt * 16 + jl;
            long cbase = (wave * 2 + t) * 16 + g * 4;
            float4 rq = *(const float4*)(R + (long)i0 * rs0 + (long)tj * rs1 + cbase);
            float4 bq = bias4[t];
            float4 vv;
            vv.x = acc[0] + bq.x + rq.x;
            vv.y = acc[1] + bq.y + rq.y;
            vv.z = acc[2] + bq.z + rq.z;
            vv.w = acc[3] + bq.w + rq.w;
            *(float4*)(out + (long)i0 * os0 + (long)tj * os1 + cbase) = vv;
        }
    }
}

// ========== fused feed-forward: out = y + silu(silu(y)@W1.T+b1)@W2.T + b2 ==========
// 96 tokens/block (grid 1536). GEMM1 A reads rotate-prefetched from global Y
// (silu in-register); GEMM2 residual prefetched one mt ahead. LDS = hs only
// (50688 B -> 3 blocks/CU).
__global__ __launch_bounds__(256, 3) void ff_fused_kernel(
    const float* __restrict__ Y,
    const unsigned short* __restrict__ W1b, const float* __restrict__ B1,
    const unsigned short* __restrict__ W2b, const float* __restrict__ B2,
    float* __restrict__ out)
{
    const int tid = threadIdx.x, wave = tid >> 6, lane = tid & 63;
    const int jl = lane & 15, g = lane >> 4;

    __shared__ __align__(16) unsigned int hs[96 * 132];   // 50688 B  silu(h) bf16

    // ---- W1 frags: wave owns cols wave*64 + t*16 .. +15 (t=0..3), KS=4
    bf16x8 w1f[4][4];
    float4 b1q[4];
#pragma unroll
    for (int t = 0; t < 4; ++t) {
        int c = wave * 64 + t * 16 + jl;
        const unsigned short* wr = W1b + (long)c * 128;
        b1q[t] = *(const float4*)(B1 + wave * 64 + t * 16 + g * 4);
#pragma unroll
        for (int ks = 0; ks < 4; ++ks) w1f[t][ks] = ldw8(wr + ks * 32 + g * 8);
    }

    const long t0 = (long)blockIdx.x * 96;

    // ---- GEMM1 (swapped) with rotate-prefetch of next mt's Y row segment
    float4 pa[8];
    {
        const float* ap = Y + (t0 + jl) * 128;
#pragma unroll
        for (int q = 0; q < 8; ++q)
            pa[q] = *(const float4*)(ap + (q >> 1) * 32 + g * 8 + (q & 1) * 4);
    }
    for (int mt = 0; mt < 6; ++mt) {
        float4 cur[8];
#pragma unroll
        for (int q = 0; q < 8; ++q) cur[q] = pa[q];
        if (mt < 5) {
            const float* apn = Y + (t0 + (mt + 1) * 16 + jl) * 128;
#pragma unroll
            for (int q = 0; q < 8; ++q)
                pa[q] = *(const float4*)(apn + (q >> 1) * 32 + g * 8 + (q & 1) * 4);
        }
        bf16x8 af[4];
#pragma unroll
        for (int ks = 0; ks < 4; ++ks) {
            float4 a0 = cur[2 * ks], a1 = cur[2 * ks + 1];
            union { unsigned int u[4]; bf16x8 v; } cv;
            cv.u[0] = pkbf(fsilu(a0.x), fsilu(a0.y));
            cv.u[1] = pkbf(fsilu(a0.z), fsilu(a0.w));
            cv.u[2] = pkbf(fsilu(a1.x), fsilu(a1.y));
            cv.u[3] = pkbf(fsilu(a1.z), fsilu(a1.w));
            af[ks] = cv.v;
        }
#pragma unroll
        for (int t = 0; t < 4; ++t) {
            f32x4 acc = {0.f, 0.f, 0.f, 0.f};
#pragma unroll
            for (int ks = 0; ks < 4; ++ks) acc = MFMA32(w1f[t][ks], af[ks], acc);
            float4 bq = b1q[t];
            float h0 = fsilu(acc[0] + bq.x), h1 = fsilu(acc[1] + bq.y);
            float h2 = fsilu(acc[2] + bq.z), h3 = fsilu(acc[3] + bq.w);
            uint2 pk = { pkbf(h0, h1), pkbf(h2, h3) };
            *(uint2*)(hs + (mt * 16 + jl) * 132 + wave * 32 + t * 8 + g * 2) = pk;
        }
    }

    // ---- W2 frags loaded here: latency hides under the barrier wait
    bf16x8 w2f[2][8];
    float4 b2q[2];
#pragma unroll
    for (int t = 0; t < 2; ++t) {
        int co = wave * 32 + t * 16 + jl;
        const unsigned short* wr = W2b + (long)co * 256;
        b2q[t] = *(const float4*)(B2 + wave * 32 + t * 16 + g * 4);
#pragma unroll
        for (int ks = 0; ks < 8; ++ks) w2f[t][ks] = ldw8(wr + ks * 32 + g * 8);
    }
    __syncthreads();

    // ---- GEMM2 (swapped): out[co][token] + b2 + residual y (residual prefetched)
    const int i0 = blockIdx.x >> 2;
    const int j0b = (blockIdx.x & 3) * 96;
    const long cb0 = wave * 32 + g * 4;

    float4 pr0, pr1;
    {
        long ad = (long)i0 * 49152 + (long)(j0b + jl) * 128 + cb0;
        pr0 = *(const float4*)(Y + ad);
        pr1 = *(const float4*)(Y + ad + 16);
    }
    for (int mt = 0; mt < 6; ++mt) {
        float4 cr0 = pr0, cr1 = pr1;
        if (mt < 5) {
            long adn = (long)i0 * 49152 + (long)(j0b + (mt + 1) * 16 + jl) * 128 + cb0;
            pr0 = *(const float4*)(Y + adn);
            pr1 = *(const float4*)(Y + adn + 16);
        }
        bf16x8 af[8];
#pragma unroll
        for (int ks = 0; ks < 8; ++ks) {
            int adw = (mt * 16 + jl) * 132 + ks * 16 + g * 4;
            uint4 x = *(const uint4*)(hs + adw);
            union { unsigned int u[4]; bf16x8 v; } cv;
            cv.u[0] = x.x; cv.u[1] = x.y; cv.u[2] = x.z; cv.u[3] = x.w;
            af[ks] = cv.v;
        }
#pragma unroll
        for (int t = 0; t < 2; ++t) {
            f32x4 acc = {0.f, 0.f, 0.f, 0.f};
#pragma unroll
            for (int ks = 0; ks < 8; ++ks) acc = MFMA32(w2f[t][ks], af[ks], acc);
            int tj = j0b + mt * 16 + jl;
            long addr = (long)i0 * 49152 + (long)tj * 128 + cb0 + t * 16;
            float4 rq = t ? cr1 : cr0;
            float4 bq = b2q[t];
            float4 vv;
            vv.x = acc[0] + bq.x + rq.x;
            vv.y = acc[1] + bq.y + rq.y;
            vv.z = acc[2] + bq.z + rq.z;
            vv.w = acc[3] + bq.w + rq.w;
            *(float4*)(out + addr) = vv;
        }
    }
}

// ---------- launch ----------
extern "C" void kernel_launch(void* const* d_in, const int* in_sizes, int n_in,
                              void* d_out, int out_size, void* d_ws, size_t ws_size,
                              hipStream_t stream)
{
    const float* edge     = (const float*)d_in[0];
    const float* r_ln_g   = (const float*)d_in[1];
    const float* r_ln_b   = (const float*)d_in[2];
    const float* r_qkv_w  = (const float*)d_in[3];
    const float* r_gate_w = (const float*)d_in[4];
    const float* r_gate_b = (const float*)d_in[5];
    const float* r_fin_w  = (const float*)d_in[6];
    const float* r_fin_b  = (const float*)d_in[7];
    const float* c_ln_g   = (const float*)d_in[8];
    const float* c_ln_b   = (const float*)d_in[9];
    const float* c_qkv_w  = (const float*)d_in[10];
    const float* c_gate_w = (const float*)d_in[11];
    const float* c_gate_b = (const float*)d_in[12];
    const float* c_fin_w  = (const float*)d_in[13];
    const float* c_fin_b  = (const float*)d_in[14];
    const float* ff_w1    = (const float*)d_in[15];
    const float* ff_b1    = (const float*)d_in[16];
    const float* ff_w2    = (const float*)d_in[17];
    const float* ff_b2    = (const float*)d_in[18];

    char* ws = (char*)d_ws;
    unsigned short* qb = (unsigned short*)ws;
    unsigned short* kb = qb + 9437184;
    unsigned short* vb = qb + 2 * 9437184;
    unsigned short* gb = qb + 3 * 9437184;
    unsigned short* attnb = (unsigned short*)(ws + 75497472);   // bf16, 18,874,368 B
    unsigned short* wcv   = (unsigned short*)(ws + 75497472 + 18874368);  // 294,912 B
    float* y    = (float*)(ws + 75497472 + 37748736);           // 75,497,472 B

    const unsigned short* wqg_r = wcv;
    const unsigned short* wqg_c = wcv + 32768;
    const unsigned short* w1b   = wcv + 65536;
    const unsigned short* w2b   = wcv + 98304;
    const unsigned short* wfin_r = wcv + 131072;
    const unsigned short* wfin_c = wcv + 139264;

    const long LD = 49152; // 384*128

    // ---- one-shot weight conversion (f32 -> bf16, q-scale baked in)
    wconv_kernel<<<288, 256, 0, stream>>>(
        r_qkv_w, r_gate_w, c_qkv_w, c_gate_w, ff_w1, ff_w2, r_fin_w, c_fin_w, wcv);

    // ---- row attention
    qkvg_kernel<<<dim3(LSEQ, 4), 256, 0, stream>>>(
        edge, LD, 128, r_ln_g, r_ln_b, wqg_r, r_gate_b, qb, kb, vb, gb);
    attn_core_kernel<<<dim3(LSEQ, NHEADS), 256, 0, stream>>>(qb, kb, vb, gb, attnb);
    fin_kernel<<<1536, 256, 0, stream>>>(
        attnb, wfin_r, r_fin_b, edge, LD, 128, y, LD, 128);

    // ---- column attention (x viewed transposed via strides)
    qkvg_kernel<<<dim3(LSEQ, 4), 256, 0, stream>>>(
        y, 128, LD, c_ln_g, c_ln_b, wqg_c, c_gate_b, qb, kb, vb, gb);
    attn_core_kernel<<<dim3(LSEQ, NHEADS), 256, 0, stream>>>(qb, kb, vb, gb, attnb);
    fin_kernel<<<1536, 256, 0, stream>>>(
        attnb, wfin_c, c_fin_b, y, 128, LD, y, 128, LD);

    // ---- fused feed-forward (96 tokens/block, pipelined)
    ff_fused_kernel<<<1536, 256, 0, stream>>>(
        y, w1b, ff_b1, w2b, ff_b2, (float*)d_out);
}

// Round 8
// 445.966 us; speedup vs baseline: 1.0595x; 1.0595x over previous
//
#include <hip/hip_runtime.h>

#define LSEQ 384
#define DIM 128
#define NHEADS 4
#define HDIM 16

typedef __attribute__((ext_vector_type(8))) short bf16x8;
typedef __attribute__((ext_vector_type(4))) short bf16x4;
typedef __attribute__((ext_vector_type(4))) float f32x4;

#define MFMA32(A,B,C) __builtin_amdgcn_mfma_f32_16x16x32_bf16(A,B,C,0,0,0)

#if __has_builtin(__builtin_amdgcn_mfma_f32_16x16x16bf16_1k)
#define HAVE_MFMA16 1
#else
#define HAVE_MFMA16 0
#endif

// ---------- helpers ----------
__device__ __forceinline__ float bf2f_lo(unsigned int u) { return __uint_as_float(u << 16); }
__device__ __forceinline__ float bf2f_hi(unsigned int u) { return __uint_as_float(u & 0xFFFF0000u); }
__device__ __forceinline__ float bf2f_s(unsigned short s) { return __uint_as_float(((unsigned int)s) << 16); }
__device__ __forceinline__ unsigned short f2bf(float f) {
    unsigned int u = __float_as_uint(f);
    u += 0x7FFFu + ((u >> 16) & 1u);   // round-to-nearest-even
    return (unsigned short)(u >> 16);
}
// pack two f32 -> one dword of 2x bf16 (RTNE), single instruction (T12 recipe)
__device__ __forceinline__ unsigned int pkbf(float a, float b) {
    unsigned int r;
    asm("v_cvt_pk_bf16_f32 %0, %1, %2" : "=v"(r) : "v"(a), "v"(b));
    return r;
}
__device__ __forceinline__ float ex2(float x) {
#if __has_builtin(__builtin_amdgcn_exp2f)
    return __builtin_amdgcn_exp2f(x);
#else
    return exp2f(x);
#endif
}
__device__ __forceinline__ float frcp(float x) {
#if __has_builtin(__builtin_amdgcn_rcpf)
    return __builtin_amdgcn_rcpf(x);
#else
    return 1.f / x;
#endif
}
__device__ __forceinline__ float fsigm(float x) {      // sigmoid(x) = 1/(1+2^(-x*log2e))
    return frcp(1.f + ex2(-1.44269504088896341f * x));
}
__device__ __forceinline__ float fsilu(float x) { return x * fsigm(x); }
__device__ __forceinline__ bf16x8 ldw8(const unsigned short* p) {
    union { uint4 x; bf16x8 v; } c;
    c.x = *(const uint4*)p;
    return c.v;
}

// ---- converted-weight layout (shorts), placed in workspace slack:
//  [0]        wqg_r [256][128]  (qkv rows 0..191 (q rows 0..63 pre-scaled), gate rows 192..255)
//  [32768]    wqg_c [256][128]
//  [65536]    w1b   [256][128]
//  [98304]    w2b   [128][256]
//  [131072]   wfin_r[128][64]
//  [139264]   wfin_c[128][64]   (total 147456 shorts = 294912 B)

// ================= wconv: one-shot f32 -> bf16 weight conversion ==========
__global__ __launch_bounds__(256) void wconv_kernel(
    const float* __restrict__ r_qkv_w, const float* __restrict__ r_gate_w,
    const float* __restrict__ c_qkv_w, const float* __restrict__ c_gate_w,
    const float* __restrict__ ff_w1, const float* __restrict__ ff_w2,
    const float* __restrict__ r_fin_w, const float* __restrict__ c_fin_w,
    unsigned short* __restrict__ wout)
{
    int idx = blockIdx.x * 256 + threadIdx.x;   // dword index, 73728 total
    const float SQ = 0.36067376022224085f;      // 0.25 * log2(e) / sqrt(HDIM) scaling for q
    float2 a;
    if (idx < 32768) {                 // wqg_r / wqg_c
        int half = idx >> 14;
        int e = (idx & 16383) * 2;
        int row = e >> 7, col = e & 127;
        const float* qkv = half ? c_qkv_w : r_qkv_w;
        const float* gw  = half ? c_gate_w : r_gate_w;
        const float* src = (row < 192) ? (qkv + (long)row * 128 + col)
                                       : (gw + (long)(row - 192) * 128 + col);
        a = *(const float2*)src;
        if (row < 64) { a.x *= SQ; a.y *= SQ; }
    } else if (idx < 49152) {          // w1b
        a = *(const float2*)(ff_w1 + (long)(idx - 32768) * 2);
    } else if (idx < 65536) {          // w2b
        a = *(const float2*)(ff_w2 + (long)(idx - 49152) * 2);
    } else if (idx < 69632) {          // wfin_r
        a = *(const float2*)(r_fin_w + (long)(idx - 65536) * 2);
    } else {                           // wfin_c
        a = *(const float2*)(c_fin_w + (long)(idx - 69632) * 2);
    }
    ((unsigned int*)wout)[idx] = pkbf(a.x, a.y);
}

// ================= qkvg: LN + qkv/gate projection via MFMA =================
// Writes q*(0.25*log2e), k, v, sigmoid(gate) as bf16 into [b][h][n][16] layout.
// Swapped operands: D[c][token] -> coalesced uint2 (4x bf16) stores.
// LN: 4 tokens in flight per wave (16-lane groups), float4 loads, 4-step shfl.
#define XSTR 138   // LDS row stride in bf16
__global__ __launch_bounds__(256, 3) void qkvg_kernel(
    const float* __restrict__ x, long sb, long sn,
    const float* __restrict__ ln_g, const float* __restrict__ ln_b,
    const unsigned short* __restrict__ wqg,      // [256][128] bf16, q-scale baked in
    const float* __restrict__ b_gate,
    unsigned short* __restrict__ qws, unsigned short* __restrict__ kws,
    unsigned short* __restrict__ vws, unsigned short* __restrict__ gws)
{
    const int b   = blockIdx.x;
    const int q4  = blockIdx.y;          // token quarter (96 tokens each)
    const int tid = threadIdx.x, wave = tid >> 6, lane = tid & 63;
    const int jl  = lane & 15, g = lane >> 4;

    __shared__ __align__(16) unsigned short xn[96 * XSTR];
    __shared__ __align__(16) unsigned short xr[96 * XSTR];

    // ---- weight B-frags (16x16x32): wave owns n-tiles wave*4 .. wave*4+3
    bf16x8 wfrag[4][4];
#pragma unroll
    for (int t = 0; t < 4; ++t) {
        int c = (wave * 4 + t) * 16 + jl;
        const unsigned short* wr = wqg + (long)c * 128;
#pragma unroll
        for (int ks = 0; ks < 4; ++ks) wfrag[t][ks] = ldw8(wr + ks * 32 + g * 8);
    }
    // gate bias: per (t, g, r) (swapped output): only wave 3 needs it
    float4 gb4[4];
    if (wave == 3) {
#pragma unroll
        for (int t = 0; t < 4; ++t) gb4[t] = *(const float4*)(b_gate + t * 16 + g * 4);
    }

    // ---- LayerNorm: quarter-wave (16 lanes) per token, 4 tokens/iter, 6 iters
    const float* xbase = x + (long)b * sb + (long)(q4 * 96) * sn;
    const float4 lgA = *(const float4*)(ln_g + jl * 8);
    const float4 lgB = *(const float4*)(ln_g + jl * 8 + 4);
    const float4 lbA = *(const float4*)(ln_b + jl * 8);
    const float4 lbB = *(const float4*)(ln_b + jl * 8 + 4);
#pragma unroll
    for (int i = 0; i < 6; ++i) {
        int tk = wave * 24 + i * 4 + g;
        const float* xp = xbase + (long)tk * sn + jl * 8;
        float4 a0 = *(const float4*)xp;
        float4 a1 = *(const float4*)(xp + 4);
        float s  = ((a0.x + a0.y) + (a0.z + a0.w)) + ((a1.x + a1.y) + (a1.z + a1.w));
        float sq = a0.x * a0.x;
        sq = fmaf(a0.y, a0.y, sq); sq = fmaf(a0.z, a0.z, sq); sq = fmaf(a0.w, a0.w, sq);
        sq = fmaf(a1.x, a1.x, sq); sq = fmaf(a1.y, a1.y, sq);
        sq = fmaf(a1.z, a1.z, sq); sq = fmaf(a1.w, a1.w, sq);
        s  += __shfl_xor(s, 1, 64);  sq += __shfl_xor(sq, 1, 64);
        s  += __shfl_xor(s, 2, 64);  sq += __shfl_xor(sq, 2, 64);
        s  += __shfl_xor(s, 4, 64);  sq += __shfl_xor(sq, 4, 64);
        s  += __shfl_xor(s, 8, 64);  sq += __shfl_xor(sq, 8, 64);
        float mean = s * (1.f / 128.f);
        float var  = sq * (1.f / 128.f) - mean * mean;
        float inv  = rsqrtf(var + 1e-5f);
        float n0 = (a0.x - mean) * inv * lgA.x + lbA.x;
        float n1 = (a0.y - mean) * inv * lgA.y + lbA.y;
        float n2 = (a0.z - mean) * inv * lgA.z + lbA.z;
        float n3 = (a0.w - mean) * inv * lgA.w + lbA.w;
        float n4 = (a1.x - mean) * inv * lgB.x + lbB.x;
        float n5 = (a1.y - mean) * inv * lgB.y + lbB.y;
        float n6 = (a1.z - mean) * inv * lgB.z + lbB.z;
        float n7 = (a1.w - mean) * inv * lgB.w + lbB.w;
        unsigned int* dn = (unsigned int*)(xn + tk * XSTR) + jl * 4;
        dn[0] = pkbf(n0, n1); dn[1] = pkbf(n2, n3);
        dn[2] = pkbf(n4, n5); dn[3] = pkbf(n6, n7);
        unsigned int* dr = (unsigned int*)(xr + tk * XSTR) + jl * 4;
        dr[0] = pkbf(a0.x, a0.y); dr[1] = pkbf(a0.z, a0.w);
        dr[2] = pkbf(a1.x, a1.y); dr[3] = pkbf(a1.z, a1.w);
    }
    __syncthreads();

    // ---- GEMM: 6 m-tiles x 4 n-tiles x 4 k-steps (16x16x32), swapped operands
    const unsigned int* a32 = (const unsigned int*)((wave == 3) ? xr : xn);
    for (int mt = 0; mt < 6; ++mt) {
        bf16x8 af[4];
#pragma unroll
        for (int ks = 0; ks < 4; ++ks) {
            int adw = (mt * 16 + jl) * (XSTR / 2) + ks * 16 + g * 4;
            union { unsigned int u[4]; bf16x8 v; } cv;
            cv.u[0] = a32[adw]; cv.u[1] = a32[adw + 1];
            cv.u[2] = a32[adw + 2]; cv.u[3] = a32[adw + 3];
            af[ks] = cv.v;
        }
#pragma unroll
        for (int t = 0; t < 4; ++t) {
            int nt = wave * 4 + t;
            f32x4 acc = {0.f, 0.f, 0.f, 0.f};
#pragma unroll
            for (int ks = 0; ks < 4; ++ks) acc = MFMA32(wfrag[t][ks], af[ks], acc);
            // D[c][token]: row (g*4+r) = feature dim, col (jl) = token
            int mat = nt >> 2, hh = nt & 3;
            int token = q4 * 96 + mt * 16 + jl;
            long base = (((long)b * NHEADS + hh) * LSEQ + token) * HDIM + g * 4;
            if (mat == 3) {
                float4 gb = gb4[t];
                float v0 = fsigm(acc[0] + gb.x), v1 = fsigm(acc[1] + gb.y);
                float v2 = fsigm(acc[2] + gb.z), v3 = fsigm(acc[3] + gb.w);
                uint2 pk = { pkbf(v0, v1), pkbf(v2, v3) };
                *(uint2*)(gws + base) = pk;
            } else {
                unsigned short* outp = (mat == 0) ? qws : (mat == 1) ? kws : vws;
                uint2 pk = { pkbf(acc[0], acc[1]), pkbf(acc[2], acc[3]) };
                *(uint2*)(outp + base) = pk;
            }
        }
    }
}

// ================= attention core: S=QK^T, softmax over j, O=P^T V, gate ===
// No LDS staging; u-outer loops with rotate-prefetch. 4 blocks/CU: measured
// sweet spot (6 blocks/CU thrashes the L1-resident Q/K/V working set — R7).
#if HAVE_MFMA16
typedef bf16x4 sfrag_t;
#define SMFMA(A,B,C) __builtin_amdgcn_mfma_f32_16x16x16bf16_1k(A,B,C,0,0,0)
__device__ __forceinline__ sfrag_t ldfragG(const unsigned short* base, int row, int g) {
    union { uint2 x; bf16x4 v; } c;
    c.x = *(const uint2*)(base + row * 16 + g * 4);
    return c.v;
}
#else
typedef bf16x8 sfrag_t;
#define SMFMA(A,B,C) MFMA32(A,B,C)
__device__ __forceinline__ sfrag_t ldfragG(const unsigned short* base, int row, int g) {
    union { uint4 x; bf16x8 v; } c;
    if (g < 2) c.x = *(const uint4*)(base + row * 16 + g * 8);
    else { c.x.x = 0; c.x.y = 0; c.x.z = 0; c.x.w = 0; }
    return c.v;
}
#endif

__global__ __launch_bounds__(256, 4) void attn_core_kernel(
    const unsigned short* __restrict__ qws, const unsigned short* __restrict__ kws,
    const unsigned short* __restrict__ vws, const unsigned short* __restrict__ gws,
    unsigned short* __restrict__ attn_out)    // bf16 [b][j][64]
{
    const int b = blockIdx.x, h = blockIdx.y;
    const int tid = threadIdx.x, wave = tid >> 6, lane = tid & 63;
    const int jl  = lane & 15, g = lane >> 4;

    __shared__ float linv[LSEQ];     // 1536 B total LDS

    const long goff = ((long)b * NHEADS + h) * (LSEQ * HDIM);
    const unsigned short* Q = qws + goff;
    const unsigned short* K = kws + goff;
    const unsigned short* V = vws + goff;

    // gate prefetch for this wave's 6 j-tiles (hide full latency under pass 1)
    uint2 gq6[6];
#pragma unroll
    for (int t = 0; t < 6; ++t)
        gq6[t] = *(const uint2*)(gws + goff + (long)((wave * 6 + t) * 16 + jl) * 16 + g * 4);

    // own-tile frags (tile = wave*6 + t)
    sfrag_t Qo[6], Ko[6];
#pragma unroll
    for (int t = 0; t < 6; ++t) {
        Qo[t] = ldfragG(Q, (wave * 6 + t) * 16 + jl, g);
        Ko[t] = ldfragG(K, (wave * 6 + t) * 16 + jl, g);
    }

    const f32x4 fz = {0.f, 0.f, 0.f, 0.f};

    // ---- pass 1: l_i = sum_j 2^(s'_ij); u outer (K-frags loaded once per u)
    float lsum[6] = {0.f, 0.f, 0.f, 0.f, 0.f, 0.f};
    {
        sfrag_t kc0 = ldfragG(K, jl, g), kc1 = ldfragG(K, 16 + jl, g);
        for (int u = 0; u < 12; ++u) {
            sfrag_t c0 = kc0, c1 = kc1;
            if (u < 11) {
                kc0 = ldfragG(K, 32 * (u + 1) + jl, g);
                kc1 = ldfragG(K, 32 * (u + 1) + 16 + jl, g);
            }
#pragma unroll
            for (int t = 0; t < 6; ++t) {
                f32x4 s0 = SMFMA(c0, Qo[t], fz);
                f32x4 s1 = SMFMA(c1, Qo[t], fz);
                lsum[t] += ((ex2(s0[0]) + ex2(s0[1])) + (ex2(s0[2]) + ex2(s0[3])))
                         + ((ex2(s1[0]) + ex2(s1[1])) + (ex2(s1[2]) + ex2(s1[3])));
            }
        }
    }
#pragma unroll
    for (int t = 0; t < 6; ++t) {
        float l = lsum[t];
        l += __shfl_xor(l, 16, 64);
        l += __shfl_xor(l, 32, 64);
        if (lane < 16) linv[(wave * 6 + t) * 16 + jl] = 1.f / l;
    }

    // prefetch u=0 of pass 2 (independent of linv)
    sfrag_t qc0 = ldfragG(Q, jl, g), qc1 = ldfragG(Q, 16 + jl, g);
    unsigned short vv[8];
#pragma unroll
    for (int p = 0; p < 4; ++p) {
        int t0 = (p < 2) ? (g * 4 + 2 * p) : (16 + g * 4 + 2 * (p - 2));
        vv[2 * p]     = V[t0 * 16 + jl];
        vv[2 * p + 1] = V[(t0 + 1) * 16 + jl];
    }
    __syncthreads();

    // ---- pass 2 (u outer): O[d][j] accumulated per j-tile; VB built per u
    f32x4 o[6];
#pragma unroll
    for (int t = 0; t < 6; ++t) o[t] = fz;

    for (int u = 0; u < 12; ++u) {
        // V-hat B-frag for this u (tau slot permutation), from prefetched raw v
        union { unsigned int w[4]; bf16x8 v; } vbu;
#pragma unroll
        for (int p = 0; p < 4; ++p) {
            int t0 = 32 * u + ((p < 2) ? (g * 4 + 2 * p) : (16 + g * 4 + 2 * (p - 2)));
            vbu.w[p] = pkbf(bf2f_s(vv[2 * p]) * linv[t0],
                            bf2f_s(vv[2 * p + 1]) * linv[t0 + 1]);
        }
        bf16x8 VB = vbu.v;
        sfrag_t c0 = qc0, c1 = qc1;
        if (u < 11) {
            qc0 = ldfragG(Q, 32 * (u + 1) + jl, g);
            qc1 = ldfragG(Q, 32 * (u + 1) + 16 + jl, g);
#pragma unroll
            for (int p = 0; p < 4; ++p) {
                int t0 = 32 * (u + 1) + ((p < 2) ? (g * 4 + 2 * p) : (16 + g * 4 + 2 * (p - 2)));
                vv[2 * p]     = V[t0 * 16 + jl];
                vv[2 * p + 1] = V[(t0 + 1) * 16 + jl];
            }
        }
#pragma unroll
        for (int t = 0; t < 6; ++t) {
            f32x4 s0 = SMFMA(c0, Ko[t], fz);
            f32x4 s1 = SMFMA(c1, Ko[t], fz);
            union { unsigned int w[4]; bf16x8 v; } pf;
            pf.w[0] = pkbf(ex2(s0[0]), ex2(s0[1]));
            pf.w[1] = pkbf(ex2(s0[2]), ex2(s0[3]));
            pf.w[2] = pkbf(ex2(s1[0]), ex2(s1[1]));
            pf.w[3] = pkbf(ex2(s1[2]), ex2(s1[3]));
            o[t] = MFMA32(VB, pf.v, o[t]);    // D[d][j]
        }
    }

    // ---- epilogue: gate & store bf16 uint2
#pragma unroll
    for (int t = 0; t < 6; ++t) {
        int jrow = (wave * 6 + t) * 16 + jl;
        uint2 gpk = gq6[t];
        float r0 = o[t][0] * bf2f_lo(gpk.x);
        float r1 = o[t][1] * bf2f_hi(gpk.x);
        float r2 = o[t][2] * bf2f_lo(gpk.y);
        float r3 = o[t][3] * bf2f_hi(gpk.y);
        uint2 pk = { pkbf(r0, r1), pkbf(r2, r3) };
        *(uint2*)(attn_out + ((long)b * LSEQ + jrow) * 64 + h * HDIM + g * 4) = pk;
    }
}

// ========== fin projection: out[t,c] = R[t,c] + bias[c] + sum_k A[t,k]*W[c,k] ==========
// A bf16 [tok][64], W bf16 [128][64]. No LDS/barriers. 4 blocks/CU (R7: 6 regressed).
__global__ __launch_bounds__(256, 4) void fin_kernel(
    const unsigned short* __restrict__ A,
    const unsigned short* __restrict__ Wb, const float* __restrict__ Bv,
    const float* __restrict__ R, long rs0, long rs1,
    float* __restrict__ out, long os0, long os1)
{
    const int tid = threadIdx.x, wave = tid >> 6, lane = tid & 63;
    const int jl = lane & 15, g = lane >> 4;

    bf16x8 wfrag[2][2];
    float4 bias4[2];
#pragma unroll
    for (int t = 0; t < 2; ++t) {
        int c = (wave * 2 + t) * 16 + jl;
        const unsigned short* wr = Wb + (long)c * 64;
        bias4[t] = *(const float4*)(Bv + (wave * 2 + t) * 16 + g * 4);
        wfrag[t][0] = ldw8(wr + g * 8);
        wfrag[t][1] = ldw8(wr + 32 + g * 8);
    }

    const long t0 = (long)blockIdx.x * 96;
    const int i0 = blockIdx.x >> 2;
    const int j0b = (blockIdx.x & 3) * 96;

    for (int mt = 0; mt < 6; ++mt) {
        const unsigned short* ap = A + (t0 + mt * 16 + jl) * 64;
        bf16x8 af0 = ldw8(ap + g * 8);
        bf16x8 af1 = ldw8(ap + 32 + g * 8);
#pragma unroll
        for (int t = 0; t < 2; ++t) {
            f32x4 acc = {0.f, 0.f, 0.f, 0.f};
            acc = MFMA32(wfrag[t][0], af0, acc);
            acc = MFMA32(wfrag[t][1], af1, acc);
            int tj = j0b + mt * 16 + jl;
            long cbase = (wave * 2 + t) * 16 + g * 4;
            float4 rq = *(const float4*)(R + (long)i0 * rs0 + (long)tj * rs1 + cbase);
            float4 bq = bias4[t];
            float4 vv;
            vv.x = acc[0] + bq.x + rq.x;
            vv.y = acc[1] + bq.y + rq.y;
            vv.z = acc[2] + bq.z + rq.z;
            vv.w = acc[3] + bq.w + rq.w;
            *(float4*)(out + (long)i0 * os0 + (long)tj * os1 + cbase) = vv;
        }
    }
}

// ========== fused feed-forward: out = y + silu(silu(y)@W1.T+b1)@W2.T + b2 ==========
// 96 tokens/block (grid 1536). GEMM1 A reads rotate-prefetched from global Y
// (silu in-register); GEMM2 residual prefetched one mt ahead. LDS = hs only
// (50688 B -> 3 blocks/CU).
__global__ __launch_bounds__(256, 3) void ff_fused_kernel(
    const float* __restrict__ Y,
    const unsigned short* __restrict__ W1b, const float* __restrict__ B1,
    const unsigned short* __restrict__ W2b, const float* __restrict__ B2,
    float* __restrict__ out)
{
    const int tid = threadIdx.x, wave = tid >> 6, lane = tid & 63;
    const int jl = lane & 15, g = lane >> 4;

    __shared__ __align__(16) unsigned int hs[96 * 132];   // 50688 B  silu(h) bf16

    // ---- W1 frags: wave owns cols wave*64 + t*16 .. +15 (t=0..3), KS=4
    bf16x8 w1f[4][4];
    float4 b1q[4];
#pragma unroll
    for (int t = 0; t < 4; ++t) {
        int c = wave * 64 + t * 16 + jl;
        const unsigned short* wr = W1b + (long)c * 128;
        b1q[t] = *(const float4*)(B1 + wave * 64 + t * 16 + g * 4);
#pragma unroll
        for (int ks = 0; ks < 4; ++ks) w1f[t][ks] = ldw8(wr + ks * 32 + g * 8);
    }

    const long t0 = (long)blockIdx.x * 96;

    // ---- GEMM1 (swapped) with rotate-prefetch of next mt's Y row segment
    float4 pa[8];
    {
        const float* ap = Y + (t0 + jl) * 128;
#pragma unroll
        for (int q = 0; q < 8; ++q)
            pa[q] = *(const float4*)(ap + (q >> 1) * 32 + g * 8 + (q & 1) * 4);
    }
    for (int mt = 0; mt < 6; ++mt) {
        float4 cur[8];
#pragma unroll
        for (int q = 0; q < 8; ++q) cur[q] = pa[q];
        if (mt < 5) {
            const float* apn = Y + (t0 + (mt + 1) * 16 + jl) * 128;
#pragma unroll
            for (int q = 0; q < 8; ++q)
                pa[q] = *(const float4*)(apn + (q >> 1) * 32 + g * 8 + (q & 1) * 4);
        }
        bf16x8 af[4];
#pragma unroll
        for (int ks = 0; ks < 4; ++ks) {
            float4 a0 = cur[2 * ks], a1 = cur[2 * ks + 1];
            union { unsigned int u[4]; bf16x8 v; } cv;
            cv.u[0] = pkbf(fsilu(a0.x), fsilu(a0.y));
            cv.u[1] = pkbf(fsilu(a0.z), fsilu(a0.w));
            cv.u[2] = pkbf(fsilu(a1.x), fsilu(a1.y));
            cv.u[3] = pkbf(fsilu(a1.z), fsilu(a1.w));
            af[ks] = cv.v;
        }
#pragma unroll
        for (int t = 0; t < 4; ++t) {
            f32x4 acc = {0.f, 0.f, 0.f, 0.f};
#pragma unroll
            for (int ks = 0; ks < 4; ++ks) acc = MFMA32(w1f[t][ks], af[ks], acc);
            float4 bq = b1q[t];
            float h0 = fsilu(acc[0] + bq.x), h1 = fsilu(acc[1] + bq.y);
            float h2 = fsilu(acc[2] + bq.z), h3 = fsilu(acc[3] + bq.w);
            uint2 pk = { pkbf(h0, h1), pkbf(h2, h3) };
            *(uint2*)(hs + (mt * 16 + jl) * 132 + wave * 32 + t * 8 + g * 2) = pk;
        }
    }

    // ---- W2 frags loaded here: latency hides under the barrier wait
    bf16x8 w2f[2][8];
    float4 b2q[2];
#pragma unroll
    for (int t = 0; t < 2; ++t) {
        int co = wave * 32 + t * 16 + jl;
        const unsigned short* wr = W2b + (long)co * 256;
        b2q[t] = *(const float4*)(B2 + wave * 32 + t * 16 + g * 4);
#pragma unroll
        for (int ks = 0; ks < 8; ++ks) w2f[t][ks] = ldw8(wr + ks * 32 + g * 8);
    }
    __syncthreads();

    // ---- GEMM2 (swapped): out[co][token] + b2 + residual y (residual prefetched)
    const int i0 = blockIdx.x >> 2;
    const int j0b = (blockIdx.x & 3) * 96;
    const long cb0 = wave * 32 + g * 4;

    float4 pr0, pr1;
    {
        long ad = (long)i0 * 49152 + (long)(j0b + jl) * 128 + cb0;
        pr0 = *(const float4*)(Y + ad);
        pr1 = *(const float4*)(Y + ad + 16);
    }
    for (int mt = 0; mt < 6; ++mt) {
        float4 cr0 = pr0, cr1 = pr1;
        if (mt < 5) {
            long adn = (long)i0 * 49152 + (long)(j0b + (mt + 1) * 16 + jl) * 128 + cb0;
            pr0 = *(const float4*)(Y + adn);
            pr1 = *(const float4*)(Y + adn + 16);
        }
        bf16x8 af[8];
#pragma unroll
        for (int ks = 0; ks < 8; ++ks) {
            int adw = (mt * 16 + jl) * 132 + ks * 16 + g * 4;
            uint4 x = *(const uint4*)(hs + adw);
            union { unsigned int u[4]; bf16x8 v; } cv;
            cv.u[0] = x.x; cv.u[1] = x.y; cv.u[2] = x.z; cv.u[3] = x.w;
            af[ks] = cv.v;
        }
#pragma unroll
        for (int t = 0; t < 2; ++t) {
            f32x4 acc = {0.f, 0.f, 0.f, 0.f};
#pragma unroll
            for (int ks = 0; ks < 8; ++ks) acc = MFMA32(w2f[t][ks], af[ks], acc);
            int tj = j0b + mt * 16 + jl;
            long addr = (long)i0 * 49152 + (long)tj * 128 + cb0 + t * 16;
            float4 rq = t ? cr1 : cr0;
            float4 bq = b2q[t];
            float4 vv;
            vv.x = acc[0] + bq.x + rq.x;
            vv.y = acc[1] + bq.y + rq.y;
            vv.z = acc[2] + bq.z + rq.z;
            vv.w = acc[3] + bq.w + rq.w;
            *(float4*)(out + addr) = vv;
        }
    }
}

// ---------- launch ----------
extern "C" void kernel_launch(void* const* d_in, const int* in_sizes, int n_in,
                              void* d_out, int out_size, void* d_ws, size_t ws_size,
                              hipStream_t stream)
{
    const float* edge     = (const float*)d_in[0];
    const float* r_ln_g   = (const float*)d_in[1];
    const float* r_ln_b   = (const float*)d_in[2];
    const float* r_qkv_w  = (const float*)d_in[3];
    const float* r_gate_w = (const float*)d_in[4];
    const float* r_gate_b = (const float*)d_in[5];
    const float* r_fin_w  = (const float*)d_in[6];
    const float* r_fin_b  = (const float*)d_in[7];
    const float* c_ln_g   = (const float*)d_in[8];
    const float* c_ln_b   = (const float*)d_in[9];
    const float* c_qkv_w  = (const float*)d_in[10];
    const float* c_gate_w = (const float*)d_in[11];
    const float* c_gate_b = (const float*)d_in[12];
    const float* c_fin_w  = (const float*)d_in[13];
    const float* c_fin_b  = (const float*)d_in[14];
    const float* ff_w1    = (const float*)d_in[15];
    const float* ff_b1    = (const float*)d_in[16];
    const float* ff_w2    = (const float*)d_in[17];
    const float* ff_b2    = (const float*)d_in[18];

    char* ws = (char*)d_ws;
    unsigned short* qb = (unsigned short*)ws;
    unsigned short* kb = qb + 9437184;
    unsigned short* vb = qb + 2 * 9437184;
    unsigned short* gb = qb + 3 * 9437184;
    unsigned short* attnb = (unsigned short*)(ws + 75497472);   // bf16, 18,874,368 B
    unsigned short* wcv   = (unsigned short*)(ws + 75497472 + 18874368);  // 294,912 B
    float* y    = (float*)(ws + 75497472 + 37748736);           // 75,497,472 B

    const unsigned short* wqg_r = wcv;
    const unsigned short* wqg_c = wcv + 32768;
    const unsigned short* w1b   = wcv + 65536;
    const unsigned short* w2b   = wcv + 98304;
    const unsigned short* wfin_r = wcv + 131072;
    const unsigned short* wfin_c = wcv + 139264;

    const long LD = 49152; // 384*128

    // ---- one-shot weight conversion (f32 -> bf16, q-scale baked in)
    wconv_kernel<<<288, 256, 0, stream>>>(
        r_qkv_w, r_gate_w, c_qkv_w, c_gate_w, ff_w1, ff_w2, r_fin_w, c_fin_w, wcv);

    // ---- row attention
    qkvg_kernel<<<dim3(LSEQ, 4), 256, 0, stream>>>(
        edge, LD, 128, r_ln_g, r_ln_b, wqg_r, r_gate_b, qb, kb, vb, gb);
    attn_core_kernel<<<dim3(LSEQ, NHEADS), 256, 0, stream>>>(qb, kb, vb, gb, attnb);
    fin_kernel<<<1536, 256, 0, stream>>>(
        attnb, wfin_r, r_fin_b, edge, LD, 128, y, LD, 128);

    // ---- column attention (x viewed transposed via strides)
    qkvg_kernel<<<dim3(LSEQ, 4), 256, 0, stream>>>(
        y, 128, LD, c_ln_g, c_ln_b, wqg_c, c_gate_b, qb, kb, vb, gb);
    attn_core_kernel<<<dim3(LSEQ, NHEADS), 256, 0, stream>>>(qb, kb, vb, gb, attnb);
    fin_kernel<<<1536, 256, 0, stream>>>(
        attnb, wfin_c, c_fin_b, y, 128, LD, y, 128, LD);

    // ---- fused feed-forward (96 tokens/block, pipelined)
    ff_fused_kernel<<<1536, 256, 0, stream>>>(
        y, w1b, ff_b1, w2b, ff_b2, (float*)d_out);
}

// Round 9
// 441.203 us; speedup vs baseline: 1.0710x; 1.0108x over previous
//
#include <hip/hip_runtime.h>

#define LSEQ 384
#define DIM 128
#define NHEADS 4
#define HDIM 16

typedef __attribute__((ext_vector_type(8))) short bf16x8;
typedef __attribute__((ext_vector_type(4))) short bf16x4;
typedef __attribute__((ext_vector_type(4))) float f32x4;

#define MFMA32(A,B,C) __builtin_amdgcn_mfma_f32_16x16x32_bf16(A,B,C,0,0,0)

#if __has_builtin(__builtin_amdgcn_mfma_f32_16x16x16bf16_1k)
#define HAVE_MFMA16 1
#else
#define HAVE_MFMA16 0
#endif

// ---------- helpers ----------
__device__ __forceinline__ float bf2f_lo(unsigned int u) { return __uint_as_float(u << 16); }
__device__ __forceinline__ float bf2f_hi(unsigned int u) { return __uint_as_float(u & 0xFFFF0000u); }
__device__ __forceinline__ float bf2f_s(unsigned short s) { return __uint_as_float(((unsigned int)s) << 16); }
__device__ __forceinline__ unsigned short f2bf(float f) {
    unsigned int u = __float_as_uint(f);
    u += 0x7FFFu + ((u >> 16) & 1u);   // round-to-nearest-even
    return (unsigned short)(u >> 16);
}
// pack two f32 -> one dword of 2x bf16 (RTNE), single instruction (T12 recipe)
__device__ __forceinline__ unsigned int pkbf(float a, float b) {
    unsigned int r;
    asm("v_cvt_pk_bf16_f32 %0, %1, %2" : "=v"(r) : "v"(a), "v"(b));
    return r;
}
__device__ __forceinline__ float ex2(float x) {
#if __has_builtin(__builtin_amdgcn_exp2f)
    return __builtin_amdgcn_exp2f(x);
#else
    return exp2f(x);
#endif
}
__device__ __forceinline__ float frcp(float x) {
#if __has_builtin(__builtin_amdgcn_rcpf)
    return __builtin_amdgcn_rcpf(x);
#else
    return 1.f / x;
#endif
}
__device__ __forceinline__ float fsigm(float x) {      // sigmoid(x) = 1/(1+2^(-x*log2e))
    return frcp(1.f + ex2(-1.44269504088896341f * x));
}
__device__ __forceinline__ float fsilu(float x) { return x * fsigm(x); }
__device__ __forceinline__ bf16x8 ldw8(const unsigned short* p) {
    union { uint4 x; bf16x8 v; } c;
    c.x = *(const uint4*)p;
    return c.v;
}

// ---- converted-weight layout (shorts), placed in workspace slack:
//  [0]        wqg_r [256][128]  (qkv rows 0..191 (q rows 0..63 pre-scaled), gate rows 192..255)
//  [32768]    wqg_c [256][128]
//  [65536]    w1b   [256][128]
//  [98304]    w2b   [128][256]
//  [131072]   wfin_r[128][64]
//  [139264]   wfin_c[128][64]   (total 147456 shorts = 294912 B)

// ================= wconv: one-shot f32 -> bf16 weight conversion ==========
__global__ __launch_bounds__(256) void wconv_kernel(
    const float* __restrict__ r_qkv_w, const float* __restrict__ r_gate_w,
    const float* __restrict__ c_qkv_w, const float* __restrict__ c_gate_w,
    const float* __restrict__ ff_w1, const float* __restrict__ ff_w2,
    const float* __restrict__ r_fin_w, const float* __restrict__ c_fin_w,
    unsigned short* __restrict__ wout)
{
    int idx = blockIdx.x * 256 + threadIdx.x;   // dword index, 73728 total
    const float SQ = 0.36067376022224085f;      // 0.25 * log2(e) / sqrt(HDIM) scaling for q
    float2 a;
    if (idx < 32768) {                 // wqg_r / wqg_c
        int half = idx >> 14;
        int e = (idx & 16383) * 2;
        int row = e >> 7, col = e & 127;
        const float* qkv = half ? c_qkv_w : r_qkv_w;
        const float* gw  = half ? c_gate_w : r_gate_w;
        const float* src = (row < 192) ? (qkv + (long)row * 128 + col)
                                       : (gw + (long)(row - 192) * 128 + col);
        a = *(const float2*)src;
        if (row < 64) { a.x *= SQ; a.y *= SQ; }
    } else if (idx < 49152) {          // w1b
        a = *(const float2*)(ff_w1 + (long)(idx - 32768) * 2);
    } else if (idx < 65536) {          // w2b
        a = *(const float2*)(ff_w2 + (long)(idx - 49152) * 2);
    } else if (idx < 69632) {          // wfin_r
        a = *(const float2*)(r_fin_w + (long)(idx - 65536) * 2);
    } else {                           // wfin_c
        a = *(const float2*)(c_fin_w + (long)(idx - 69632) * 2);
    }
    ((unsigned int*)wout)[idx] = pkbf(a.x, a.y);
}

// ================= qkvg: LN + qkv/gate projection via MFMA =================
// Writes q*(0.25*log2e), k, v, sigmoid(gate) as bf16 into [b][h][n][16] layout.
// Swapped operands: D[c][token] -> coalesced uint2 (4x bf16) stores.
// LN: 4 tokens in flight per wave (16-lane groups), float4 loads, 4-step shfl.
#define XSTR 138   // LDS row stride in bf16
__global__ __launch_bounds__(256, 3) void qkvg_kernel(
    const float* __restrict__ x, long sb, long sn,
    const float* __restrict__ ln_g, const float* __restrict__ ln_b,
    const unsigned short* __restrict__ wqg,      // [256][128] bf16, q-scale baked in
    const float* __restrict__ b_gate,
    unsigned short* __restrict__ qws, unsigned short* __restrict__ kws,
    unsigned short* __restrict__ vws, unsigned short* __restrict__ gws)
{
    const int b   = blockIdx.x;
    const int q4  = blockIdx.y;          // token quarter (96 tokens each)
    const int tid = threadIdx.x, wave = tid >> 6, lane = tid & 63;
    const int jl  = lane & 15, g = lane >> 4;

    __shared__ __align__(16) unsigned short xn[96 * XSTR];
    __shared__ __align__(16) unsigned short xr[96 * XSTR];

    // ---- weight B-frags (16x16x32): wave owns n-tiles wave*4 .. wave*4+3
    bf16x8 wfrag[4][4];
#pragma unroll
    for (int t = 0; t < 4; ++t) {
        int c = (wave * 4 + t) * 16 + jl;
        const unsigned short* wr = wqg + (long)c * 128;
#pragma unroll
        for (int ks = 0; ks < 4; ++ks) wfrag[t][ks] = ldw8(wr + ks * 32 + g * 8);
    }
    // gate bias: per (t, g, r) (swapped output): only wave 3 needs it
    float4 gb4[4];
    if (wave == 3) {
#pragma unroll
        for (int t = 0; t < 4; ++t) gb4[t] = *(const float4*)(b_gate + t * 16 + g * 4);
    }

    // ---- LayerNorm: quarter-wave (16 lanes) per token, 4 tokens/iter, 6 iters
    const float* xbase = x + (long)b * sb + (long)(q4 * 96) * sn;
    const float4 lgA = *(const float4*)(ln_g + jl * 8);
    const float4 lgB = *(const float4*)(ln_g + jl * 8 + 4);
    const float4 lbA = *(const float4*)(ln_b + jl * 8);
    const float4 lbB = *(const float4*)(ln_b + jl * 8 + 4);
#pragma unroll
    for (int i = 0; i < 6; ++i) {
        int tk = wave * 24 + i * 4 + g;
        const float* xp = xbase + (long)tk * sn + jl * 8;
        float4 a0 = *(const float4*)xp;
        float4 a1 = *(const float4*)(xp + 4);
        float s  = ((a0.x + a0.y) + (a0.z + a0.w)) + ((a1.x + a1.y) + (a1.z + a1.w));
        float sq = a0.x * a0.x;
        sq = fmaf(a0.y, a0.y, sq); sq = fmaf(a0.z, a0.z, sq); sq = fmaf(a0.w, a0.w, sq);
        sq = fmaf(a1.x, a1.x, sq); sq = fmaf(a1.y, a1.y, sq);
        sq = fmaf(a1.z, a1.z, sq); sq = fmaf(a1.w, a1.w, sq);
        s  += __shfl_xor(s, 1, 64);  sq += __shfl_xor(sq, 1, 64);
        s  += __shfl_xor(s, 2, 64);  sq += __shfl_xor(sq, 2, 64);
        s  += __shfl_xor(s, 4, 64);  sq += __shfl_xor(sq, 4, 64);
        s  += __shfl_xor(s, 8, 64);  sq += __shfl_xor(sq, 8, 64);
        float mean = s * (1.f / 128.f);
        float var  = sq * (1.f / 128.f) - mean * mean;
        float inv  = rsqrtf(var + 1e-5f);
        float n0 = (a0.x - mean) * inv * lgA.x + lbA.x;
        float n1 = (a0.y - mean) * inv * lgA.y + lbA.y;
        float n2 = (a0.z - mean) * inv * lgA.z + lbA.z;
        float n3 = (a0.w - mean) * inv * lgA.w + lbA.w;
        float n4 = (a1.x - mean) * inv * lgB.x + lbB.x;
        float n5 = (a1.y - mean) * inv * lgB.y + lbB.y;
        float n6 = (a1.z - mean) * inv * lgB.z + lbB.z;
        float n7 = (a1.w - mean) * inv * lgB.w + lbB.w;
        unsigned int* dn = (unsigned int*)(xn + tk * XSTR) + jl * 4;
        dn[0] = pkbf(n0, n1); dn[1] = pkbf(n2, n3);
        dn[2] = pkbf(n4, n5); dn[3] = pkbf(n6, n7);
        unsigned int* dr = (unsigned int*)(xr + tk * XSTR) + jl * 4;
        dr[0] = pkbf(a0.x, a0.y); dr[1] = pkbf(a0.z, a0.w);
        dr[2] = pkbf(a1.x, a1.y); dr[3] = pkbf(a1.z, a1.w);
    }
    __syncthreads();

    // ---- GEMM: 6 m-tiles x 4 n-tiles x 4 k-steps (16x16x32), swapped operands
    const unsigned int* a32 = (const unsigned int*)((wave == 3) ? xr : xn);
    for (int mt = 0; mt < 6; ++mt) {
        bf16x8 af[4];
#pragma unroll
        for (int ks = 0; ks < 4; ++ks) {
            int adw = (mt * 16 + jl) * (XSTR / 2) + ks * 16 + g * 4;
            union { unsigned int u[4]; bf16x8 v; } cv;
            cv.u[0] = a32[adw]; cv.u[1] = a32[adw + 1];
            cv.u[2] = a32[adw + 2]; cv.u[3] = a32[adw + 3];
            af[ks] = cv.v;
        }
#pragma unroll
        for (int t = 0; t < 4; ++t) {
            int nt = wave * 4 + t;
            f32x4 acc = {0.f, 0.f, 0.f, 0.f};
#pragma unroll
            for (int ks = 0; ks < 4; ++ks) acc = MFMA32(wfrag[t][ks], af[ks], acc);
            // D[c][token]: row (g*4+r) = feature dim, col (jl) = token
            int mat = nt >> 2, hh = nt & 3;
            int token = q4 * 96 + mt * 16 + jl;
            long base = (((long)b * NHEADS + hh) * LSEQ + token) * HDIM + g * 4;
            if (mat == 3) {
                float4 gb = gb4[t];
                float v0 = fsigm(acc[0] + gb.x), v1 = fsigm(acc[1] + gb.y);
                float v2 = fsigm(acc[2] + gb.z), v3 = fsigm(acc[3] + gb.w);
                uint2 pk = { pkbf(v0, v1), pkbf(v2, v3) };
                *(uint2*)(gws + base) = pk;
            } else {
                unsigned short* outp = (mat == 0) ? qws : (mat == 1) ? kws : vws;
                uint2 pk = { pkbf(acc[0], acc[1]), pkbf(acc[2], acc[3]) };
                *(uint2*)(outp + base) = pk;
            }
        }
    }
}

// ================= attention core: S=QK^T, softmax over j, O=P^T V, gate ===
// No LDS staging; u-outer loops with rotate-prefetch. 4 blocks/CU: measured
// sweet spot (6 blocks/CU thrashes the L1-resident Q/K/V working set — R7).
#if HAVE_MFMA16
typedef bf16x4 sfrag_t;
#define SMFMA(A,B,C) __builtin_amdgcn_mfma_f32_16x16x16bf16_1k(A,B,C,0,0,0)
__device__ __forceinline__ sfrag_t ldfragG(const unsigned short* base, int row, int g) {
    union { uint2 x; bf16x4 v; } c;
    c.x = *(const uint2*)(base + row * 16 + g * 4);
    return c.v;
}
#else
typedef bf16x8 sfrag_t;
#define SMFMA(A,B,C) MFMA32(A,B,C)
__device__ __forceinline__ sfrag_t ldfragG(const unsigned short* base, int row, int g) {
    union { uint4 x; bf16x8 v; } c;
    if (g < 2) c.x = *(const uint4*)(base + row * 16 + g * 8);
    else { c.x.x = 0; c.x.y = 0; c.x.z = 0; c.x.w = 0; }
    return c.v;
}
#endif

__global__ __launch_bounds__(256, 4) void attn_core_kernel(
    const unsigned short* __restrict__ qws, const unsigned short* __restrict__ kws,
    const unsigned short* __restrict__ vws, const unsigned short* __restrict__ gws,
    unsigned short* __restrict__ attn_out)    // bf16 [b][j][64]
{
    const int b = blockIdx.x, h = blockIdx.y;
    const int tid = threadIdx.x, wave = tid >> 6, lane = tid & 63;
    const int jl  = lane & 15, g = lane >> 4;

    __shared__ float linv[LSEQ];     // 1536 B total LDS

    const long goff = ((long)b * NHEADS + h) * (LSEQ * HDIM);
    const unsigned short* Q = qws + goff;
    const unsigned short* K = kws + goff;
    const unsigned short* V = vws + goff;

    // gate prefetch for this wave's 6 j-tiles (hide full latency under pass 1)
    uint2 gq6[6];
#pragma unroll
    for (int t = 0; t < 6; ++t)
        gq6[t] = *(const uint2*)(gws + goff + (long)((wave * 6 + t) * 16 + jl) * 16 + g * 4);

    // own-tile frags (tile = wave*6 + t)
    sfrag_t Qo[6], Ko[6];
#pragma unroll
    for (int t = 0; t < 6; ++t) {
        Qo[t] = ldfragG(Q, (wave * 6 + t) * 16 + jl, g);
        Ko[t] = ldfragG(K, (wave * 6 + t) * 16 + jl, g);
    }

    const f32x4 fz = {0.f, 0.f, 0.f, 0.f};

    // ---- pass 1: l_i = sum_j 2^(s'_ij); u outer (K-frags loaded once per u)
    float lsum[6] = {0.f, 0.f, 0.f, 0.f, 0.f, 0.f};
    {
        sfrag_t kc0 = ldfragG(K, jl, g), kc1 = ldfragG(K, 16 + jl, g);
        for (int u = 0; u < 12; ++u) {
            sfrag_t c0 = kc0, c1 = kc1;
            if (u < 11) {
                kc0 = ldfragG(K, 32 * (u + 1) + jl, g);
                kc1 = ldfragG(K, 32 * (u + 1) + 16 + jl, g);
            }
#pragma unroll
            for (int t = 0; t < 6; ++t) {
                f32x4 s0 = SMFMA(c0, Qo[t], fz);
                f32x4 s1 = SMFMA(c1, Qo[t], fz);
                lsum[t] += ((ex2(s0[0]) + ex2(s0[1])) + (ex2(s0[2]) + ex2(s0[3])))
                         + ((ex2(s1[0]) + ex2(s1[1])) + (ex2(s1[2]) + ex2(s1[3])));
            }
        }
    }
#pragma unroll
    for (int t = 0; t < 6; ++t) {
        float l = lsum[t];
        l += __shfl_xor(l, 16, 64);
        l += __shfl_xor(l, 32, 64);
        if (lane < 16) linv[(wave * 6 + t) * 16 + jl] = 1.f / l;
    }

    // prefetch u=0 of pass 2 (independent of linv)
    sfrag_t qc0 = ldfragG(Q, jl, g), qc1 = ldfragG(Q, 16 + jl, g);
    unsigned short vv[8];
#pragma unroll
    for (int p = 0; p < 4; ++p) {
        int t0 = (p < 2) ? (g * 4 + 2 * p) : (16 + g * 4 + 2 * (p - 2));
        vv[2 * p]     = V[t0 * 16 + jl];
        vv[2 * p + 1] = V[(t0 + 1) * 16 + jl];
    }
    __syncthreads();

    // ---- pass 2 (u outer): O[d][j] accumulated per j-tile; VB built per u
    f32x4 o[6];
#pragma unroll
    for (int t = 0; t < 6; ++t) o[t] = fz;

    for (int u = 0; u < 12; ++u) {
        // V-hat B-frag for this u (tau slot permutation), from prefetched raw v
        union { unsigned int w[4]; bf16x8 v; } vbu;
#pragma unroll
        for (int p = 0; p < 4; ++p) {
            int t0 = 32 * u + ((p < 2) ? (g * 4 + 2 * p) : (16 + g * 4 + 2 * (p - 2)));
            vbu.w[p] = pkbf(bf2f_s(vv[2 * p]) * linv[t0],
                            bf2f_s(vv[2 * p + 1]) * linv[t0 + 1]);
        }
        bf16x8 VB = vbu.v;
        sfrag_t c0 = qc0, c1 = qc1;
        if (u < 11) {
            qc0 = ldfragG(Q, 32 * (u + 1) + jl, g);
            qc1 = ldfragG(Q, 32 * (u + 1) + 16 + jl, g);
#pragma unroll
            for (int p = 0; p < 4; ++p) {
                int t0 = 32 * (u + 1) + ((p < 2) ? (g * 4 + 2 * p) : (16 + g * 4 + 2 * (p - 2)));
                vv[2 * p]     = V[t0 * 16 + jl];
                vv[2 * p + 1] = V[(t0 + 1) * 16 + jl];
            }
        }
#pragma unroll
        for (int t = 0; t < 6; ++t) {
            f32x4 s0 = SMFMA(c0, Ko[t], fz);
            f32x4 s1 = SMFMA(c1, Ko[t], fz);
            union { unsigned int w[4]; bf16x8 v; } pf;
            pf.w[0] = pkbf(ex2(s0[0]), ex2(s0[1]));
            pf.w[1] = pkbf(ex2(s0[2]), ex2(s0[3]));
            pf.w[2] = pkbf(ex2(s1[0]), ex2(s1[1]));
            pf.w[3] = pkbf(ex2(s1[2]), ex2(s1[3]));
            o[t] = MFMA32(VB, pf.v, o[t]);    // D[d][j]
        }
    }

    // ---- epilogue: gate & store bf16 uint2
#pragma unroll
    for (int t = 0; t < 6; ++t) {
        int jrow = (wave * 6 + t) * 16 + jl;
        uint2 gpk = gq6[t];
        float r0 = o[t][0] * bf2f_lo(gpk.x);
        float r1 = o[t][1] * bf2f_hi(gpk.x);
        float r2 = o[t][2] * bf2f_lo(gpk.y);
        float r3 = o[t][3] * bf2f_hi(gpk.y);
        uint2 pk = { pkbf(r0, r1), pkbf(r2, r3) };
        *(uint2*)(attn_out + ((long)b * LSEQ + jrow) * 64 + h * HDIM + g * 4) = pk;
    }
}

// ========== fin projection (ROW path): out[t,c] = R[t,c] + b[c] + A@W ==========
// A bf16 [tok][64], W bf16 [128][64]. No LDS/barriers. 4 blocks/CU.
__global__ __launch_bounds__(256, 4) void fin_kernel(
    const unsigned short* __restrict__ A,
    const unsigned short* __restrict__ Wb, const float* __restrict__ Bv,
    const float* __restrict__ R, long rs0, long rs1,
    float* __restrict__ out, long os0, long os1)
{
    const int tid = threadIdx.x, wave = tid >> 6, lane = tid & 63;
    const int jl = lane & 15, g = lane >> 4;

    bf16x8 wfrag[2][2];
    float4 bias4[2];
#pragma unroll
    for (int t = 0; t < 2; ++t) {
        int c = (wave * 2 + t) * 16 + jl;
        const unsigned short* wr = Wb + (long)c * 64;
        bias4[t] = *(const float4*)(Bv + (wave * 2 + t) * 16 + g * 4);
        wfrag[t][0] = ldw8(wr + g * 8);
        wfrag[t][1] = ldw8(wr + 32 + g * 8);
    }

    const long t0 = (long)blockIdx.x * 96;
    const int i0 = blockIdx.x >> 2;
    const int j0b = (blockIdx.x & 3) * 96;

    for (int mt = 0; mt < 6; ++mt) {
        const unsigned short* ap = A + (t0 + mt * 16 + jl) * 64;
        bf16x8 af0 = ldw8(ap + g * 8);
        bf16x8 af1 = ldw8(ap + 32 + g * 8);
#pragma unroll
        for (int t = 0; t < 2; ++t) {
            f32x4 acc = {0.f, 0.f, 0.f, 0.f};
            acc = MFMA32(wfrag[t][0], af0, acc);
            acc = MFMA32(wfrag[t][1], af1, acc);
            int tj = j0b + mt * 16 + jl;
            long cbase = (wave * 2 + t) * 16 + g * 4;
            float4 rq = *(const float4*)(R + (long)i0 * rs0 + (long)tj * rs1 + cbase);
            float4 bq = bias4[t];
            float4 vv;
            vv.x = acc[0] + bq.x + rq.x;
            vv.y = acc[1] + bq.y + rq.y;
            vv.z = acc[2] + bq.z + rq.z;
            vv.w = acc[3] + bq.w + rq.w;
            *(float4*)(out + (long)i0 * os0 + (long)tj * os1 + cbase) = vv;
        }
    }
}

// ========== fused column-fin + feed-forward ==========
// Row-major tiling: block = row i0, 96 cols. fin reads attnb TRANSPOSED
// (scattered 16B, L3-resident 18.9MB — the smallest stream); residual R and
// d_out are coalesced float4. y lives in 48 VGPRs (never touches HBM); FF
// runs split-K over two 128-col halves of h through one half-size LDS buffer.
// LDS 50688 B -> 3 blocks/CU. Numerics bit-identical to fin_c + ff chain.
__global__ __launch_bounds__(256, 3) void finff_kernel(
    const unsigned short* __restrict__ A,      // attnb, column-attn token order
    const unsigned short* __restrict__ Wfin, const float* __restrict__ Bfin,
    const float* __restrict__ R,               // y from row attention (row-major)
    const unsigned short* __restrict__ W1b, const float* __restrict__ B1,
    const unsigned short* __restrict__ W2b, const float* __restrict__ B2,
    float* __restrict__ out)
{
    const int tid = threadIdx.x, wave = tid >> 6, lane = tid & 63;
    const int jl = lane & 15, g = lane >> 4;

    __shared__ __align__(16) unsigned int xs[96 * 66];    // silu(y) bf16, 25344 B
    __shared__ __align__(16) unsigned int hsh[96 * 66];   // silu(h) half, 25344 B

    const int i0  = blockIdx.x >> 2;          // row
    const int j0b = (blockIdx.x & 3) * 96;    // col base

    // ---- phase 0: fin GEMM -> y in regs; silu(y) -> xs
    f32x4 yreg[6][2];
    {
        bf16x8 wf[2][2];
        float4 bf4[2];
#pragma unroll
        for (int t = 0; t < 2; ++t) {
            int c = (wave * 2 + t) * 16 + jl;
            const unsigned short* wr = Wfin + (long)c * 64;
            wf[t][0] = ldw8(wr + g * 8);
            wf[t][1] = ldw8(wr + 32 + g * 8);
            bf4[t] = *(const float4*)(Bfin + (wave * 2 + t) * 16 + g * 4);
        }
#pragma unroll
        for (int mt = 0; mt < 6; ++mt) {
            int col = j0b + mt * 16 + jl;
            const unsigned short* ap = A + ((long)col * 384 + i0) * 64;  // transposed read
            bf16x8 a0 = ldw8(ap + g * 8);
            bf16x8 a1 = ldw8(ap + 32 + g * 8);
#pragma unroll
            for (int t = 0; t < 2; ++t) {
                f32x4 acc = {0.f, 0.f, 0.f, 0.f};
                acc = MFMA32(wf[t][0], a0, acc);
                acc = MFMA32(wf[t][1], a1, acc);
                long cbase = (wave * 2 + t) * 16 + g * 4;
                float4 rq = *(const float4*)(R + (long)i0 * 49152 + (long)col * 128 + cbase);
                float4 bq = bf4[t];
                f32x4 yv;
                yv[0] = acc[0] + bq.x + rq.x;
                yv[1] = acc[1] + bq.y + rq.y;
                yv[2] = acc[2] + bq.z + rq.z;
                yv[3] = acc[3] + bq.w + rq.w;
                yreg[mt][t] = yv;
                unsigned int* dx = xs + (mt * 16 + jl) * 66 + wave * 16 + t * 8 + g * 2;
                dx[0] = pkbf(fsilu(yv[0]), fsilu(yv[1]));
                dx[1] = pkbf(fsilu(yv[2]), fsilu(yv[3]));
            }
        }
    }
    __syncthreads();

    // ---- FF: split-K over two 128-col halves of h
    f32x4 acc2[6][2];
#pragma unroll
    for (int mt = 0; mt < 6; ++mt) {
        acc2[mt][0] = (f32x4){0.f, 0.f, 0.f, 0.f};
        acc2[mt][1] = (f32x4){0.f, 0.f, 0.f, 0.f};
    }

#pragma unroll
    for (int half = 0; half < 2; ++half) {
        // GEMM1: h cols hc = half*128 + wave*32 + t*16 + jl
        bf16x8 w1f[2][4];
        float4 b1q[2];
#pragma unroll
        for (int t = 0; t < 2; ++t) {
            int hc = half * 128 + wave * 32 + t * 16 + jl;
            const unsigned short* wr = W1b + (long)hc * 128;
#pragma unroll
            for (int ks = 0; ks < 4; ++ks) w1f[t][ks] = ldw8(wr + ks * 32 + g * 8);
            b1q[t] = *(const float4*)(B1 + half * 128 + wave * 32 + t * 16 + g * 4);
        }
        if (half == 1) __syncthreads();   // all half-0 GEMM2 reads of hsh done
#pragma unroll
        for (int mt = 0; mt < 6; ++mt) {
            bf16x8 af[4];
#pragma unroll
            for (int ks = 0; ks < 4; ++ks) {
                union { uint4 x; bf16x8 v; } cv;
                cv.x = *(const uint4*)(xs + (mt * 16 + jl) * 66 + ks * 16 + g * 4);
                af[ks] = cv.v;
            }
#pragma unroll
            for (int t = 0; t < 2; ++t) {
                f32x4 acc = {0.f, 0.f, 0.f, 0.f};
#pragma unroll
                for (int ks = 0; ks < 4; ++ks) acc = MFMA32(w1f[t][ks], af[ks], acc);
                float4 bq = b1q[t];
                unsigned int* dh = hsh + (mt * 16 + jl) * 66 + wave * 16 + t * 8 + g * 2;
                dh[0] = pkbf(fsilu(acc[0] + bq.x), fsilu(acc[1] + bq.y));
                dh[1] = pkbf(fsilu(acc[2] + bq.z), fsilu(acc[3] + bq.w));
            }
        }
        __syncthreads();
        // GEMM2 partial: co = wave*32 + t*16 + jl, k-range = half*128..+128
        bf16x8 w2f[2][4];
#pragma unroll
        for (int t = 0; t < 2; ++t) {
            int co = wave * 32 + t * 16 + jl;
            const unsigned short* wr = W2b + (long)co * 256 + half * 128;
#pragma unroll
            for (int ks = 0; ks < 4; ++ks) w2f[t][ks] = ldw8(wr + ks * 32 + g * 8);
        }
#pragma unroll
        for (int mt = 0; mt < 6; ++mt) {
            bf16x8 af[4];
#pragma unroll
            for (int ks = 0; ks < 4; ++ks) {
                union { uint4 x; bf16x8 v; } cv;
                cv.x = *(const uint4*)(hsh + (mt * 16 + jl) * 66 + ks * 16 + g * 4);
                af[ks] = cv.v;
            }
#pragma unroll
            for (int t = 0; t < 2; ++t) {
#pragma unroll
                for (int ks = 0; ks < 4; ++ks)
                    acc2[mt][t] = MFMA32(w2f[t][ks], af[ks], acc2[mt][t]);
            }
        }
    }

    // ---- epilogue: out = ffn2 + b2 + y  (coalesced float4)
    float4 b2q[2];
#pragma unroll
    for (int t = 0; t < 2; ++t)
        b2q[t] = *(const float4*)(B2 + wave * 32 + t * 16 + g * 4);
#pragma unroll
    for (int mt = 0; mt < 6; ++mt) {
        int col = j0b + mt * 16 + jl;
#pragma unroll
        for (int t = 0; t < 2; ++t) {
            long addr = (long)i0 * 49152 + (long)col * 128 + wave * 32 + t * 16 + g * 4;
            float4 bq = b2q[t];
            f32x4 a2 = acc2[mt][t];
            f32x4 yv = yreg[mt][t];
            float4 vv;
            vv.x = a2[0] + bq.x + yv[0];
            vv.y = a2[1] + bq.y + yv[1];
            vv.z = a2[2] + bq.z + yv[2];
            vv.w = a2[3] + bq.w + yv[3];
            *(float4*)(out + addr) = vv;
        }
    }
}

// ---------- launch ----------
extern "C" void kernel_launch(void* const* d_in, const int* in_sizes, int n_in,
                              void* d_out, int out_size, void* d_ws, size_t ws_size,
                              hipStream_t stream)
{
    const float* edge     = (const float*)d_in[0];
    const float* r_ln_g   = (const float*)d_in[1];
    const float* r_ln_b   = (const float*)d_in[2];
    const float* r_qkv_w  = (const float*)d_in[3];
    const float* r_gate_w = (const float*)d_in[4];
    const float* r_gate_b = (const float*)d_in[5];
    const float* r_fin_w  = (const float*)d_in[6];
    const float* r_fin_b  = (const float*)d_in[7];
    const float* c_ln_g   = (const float*)d_in[8];
    const float* c_ln_b   = (const float*)d_in[9];
    const float* c_qkv_w  = (const float*)d_in[10];
    const float* c_gate_w = (const float*)d_in[11];
    const float* c_gate_b = (const float*)d_in[12];
    const float* c_fin_w  = (const float*)d_in[13];
    const float* c_fin_b  = (const float*)d_in[14];
    const float* ff_w1    = (const float*)d_in[15];
    const float* ff_b1    = (const float*)d_in[16];
    const float* ff_w2    = (const float*)d_in[17];
    const float* ff_b2    = (const float*)d_in[18];

    char* ws = (char*)d_ws;
    unsigned short* qb = (unsigned short*)ws;
    unsigned short* kb = qb + 9437184;
    unsigned short* vb = qb + 2 * 9437184;
    unsigned short* gb = qb + 3 * 9437184;
    unsigned short* attnb = (unsigned short*)(ws + 75497472);   // bf16, 18,874,368 B
    unsigned short* wcv   = (unsigned short*)(ws + 75497472 + 18874368);  // 294,912 B
    float* y    = (float*)(ws + 75497472 + 37748736);           // 75,497,472 B

    const unsigned short* wqg_r = wcv;
    const unsigned short* wqg_c = wcv + 32768;
    const unsigned short* w1b   = wcv + 65536;
    const unsigned short* w2b   = wcv + 98304;
    const unsigned short* wfin_r = wcv + 131072;
    const unsigned short* wfin_c = wcv + 139264;

    const long LD = 49152; // 384*128

    // ---- one-shot weight conversion (f32 -> bf16, q-scale baked in)
    wconv_kernel<<<288, 256, 0, stream>>>(
        r_qkv_w, r_gate_w, c_qkv_w, c_gate_w, ff_w1, ff_w2, r_fin_w, c_fin_w, wcv);

    // ---- row attention
    qkvg_kernel<<<dim3(LSEQ, 4), 256, 0, stream>>>(
        edge, LD, 128, r_ln_g, r_ln_b, wqg_r, r_gate_b, qb, kb, vb, gb);
    attn_core_kernel<<<dim3(LSEQ, NHEADS), 256, 0, stream>>>(qb, kb, vb, gb, attnb);
    fin_kernel<<<1536, 256, 0, stream>>>(
        attnb, wfin_r, r_fin_b, edge, LD, 128, y, LD, 128);

    // ---- column attention (x viewed transposed via strides)
    qkvg_kernel<<<dim3(LSEQ, 4), 256, 0, stream>>>(
        y, 128, LD, c_ln_g, c_ln_b, wqg_c, c_gate_b, qb, kb, vb, gb);
    attn_core_kernel<<<dim3(LSEQ, NHEADS), 256, 0, stream>>>(qb, kb, vb, gb, attnb);

    // ---- fused column-fin + feed-forward (y never round-trips HBM)
    finff_kernel<<<1536, 256, 0, stream>>>(
        attnb, wfin_c, c_fin_b, y, w1b, ff_b1, w2b, ff_b2, (float*)d_out);
}